// Round 7
// baseline (520.537 us; speedup 1.0000x reference)
//
#include <hip/hip_runtime.h>
#include <math.h>

#define N_CODES 4096
#define N_EDGES 8192
#define EMB     128
#define NHEAD   4
#define NNZ     65536
#define K_TOP   6553            // int(0.1 * 65536)
#define K_SAMP  820             // ceil(K_TOP / 8) for the 1/8-sampled histogram
#define S_TOTAL 33554432        // 4096 * 8192
#define NBINS   8192            // 32 KB LDS histogram
#define NREP    8               // global hist replicas (256 hist blocks / 8 = 32/replica)
#define CAP2    131072          // candidate cap (pool ~50k at 14-bin slack)
#define SLACK_BINS 14           // 12 (fp16 + GEMM noise) + 2 (1/8-sampling margin)
#define TIE_CAP 1024
#define LBUF    4096            // per-block candidate buffer (16 KB LDS)
#define SAMP_ITEMS (S_TOTAL / 8 / 8)   // 524288 sampled f16x8 items
#define WBLK    (CAP2 / 256)    // 512 write blocks in the fused write/scatter kernel

typedef _Float16 f16_t;
typedef __attribute__((ext_vector_type(8))) _Float16 f16x8;
typedef __attribute__((ext_vector_type(4))) float f32x4;

// ---------------- threefry2x32, JAX partitionable scheme, 32-bit path ----------------
__device__ __forceinline__ unsigned rotl32(unsigned v, int r) {
  return (v << r) | (v >> (32 - r));
}

__device__ float jax_u42(unsigned pos) {
  const unsigned ks0 = 0u, ks1 = 42u, ks2 = 0x1BD11BDAu ^ 0u ^ 42u;
  unsigned x0 = 0u  + ks0;
  unsigned x1 = pos + ks1;
#define TFR(r) { x0 += x1; x1 = rotl32(x1, (r)); x1 ^= x0; }
  TFR(13) TFR(15) TFR(26) TFR(6)   x0 += ks1; x1 += ks2 + 1u;
  TFR(17) TFR(29) TFR(16) TFR(24)  x0 += ks2; x1 += ks0 + 2u;
  TFR(13) TFR(15) TFR(26) TFR(6)   x0 += ks0; x1 += ks1 + 3u;
  TFR(17) TFR(29) TFR(16) TFR(24)  x0 += ks1; x1 += ks2 + 4u;
  TFR(13) TFR(15) TFR(26) TFR(6)   x0 += ks2; x1 += ks0 + 5u;
#undef TFR
  unsigned bits = x0 ^ x1;
  unsigned fb = (bits >> 9) | 0x3f800000u;
  float f = __uint_as_float(fb) - 1.0f;
  const float minv = 1e-6f;
  const float maxv = (float)(1.0 - 1e-6);
  float u = f * (maxv - minv) + minv;
  return fmaxf(minv, u);
}

__device__ float mask_val(float p, unsigned pos) {
  float u = jax_u42(pos);
  float l = (logf(p) - log1pf(-p) + logf(u) - log1pf(-u)) * 2.0f; // /TEMP, TEMP=0.5
  return 1.0f / (1.0f + expf(-l));
}

// f64 -> u64 monotone key (larger double <=> larger key)
__device__ __forceinline__ unsigned long long f64key(double v) {
  long long b = __double_as_longlong(v);
  return (b < 0) ? ~(unsigned long long)b
                 : ((unsigned long long)b | 0x8000000000000000ULL);
}

// ---------------- K1: per-edge counts ----------------
__global__ void count_k(const int* __restrict__ E, int* __restrict__ cnt) {
  int i = blockIdx.x * blockDim.x + threadIdx.x;
  if (i < NNZ) atomicAdd(&cnt[E[i]], 1);
}

// ---------------- K2: exclusive scan of 8192 counts ----------------
__global__ __launch_bounds__(1024) void scan_k(const int* __restrict__ cnt,
                                               int* __restrict__ offs) {
  __shared__ int part[1024];
  int t = threadIdx.x;
  int local[8]; int s = 0;
  for (int j = 0; j < 8; ++j) { local[j] = cnt[t * 8 + j]; s += local[j]; }
  part[t] = s; __syncthreads();
  int v = s;
  for (int o = 1; o < 1024; o <<= 1) {
    int add = (t >= o) ? part[t - o] : 0;
    __syncthreads();
    v += add; part[t] = v;
    __syncthreads();
  }
  int base = v - s;
  for (int j = 0; j < 8; ++j) { offs[t * 8 + j] = base; base += local[j]; }
}

// ---------------- K3: bucket scatter (CSR) ----------------
__global__ void scatter_k(const int* __restrict__ E, const int* __restrict__ offs,
                          int* __restrict__ cursor, int* __restrict__ bucket) {
  int i = blockIdx.x * blockDim.x + threadIdx.x;
  if (i < NNZ) {
    int e = E[i];
    int p = atomicAdd(&cursor[e], 1);
    bucket[offs[e] + p] = i;
  }
}

// ---------------- K4: FUSED prep — edge path (blocks < N_EDGES) + node path ----------------
__global__ __launch_bounds__(128) void prep_k(const float* __restrict__ X,
                                              const int* __restrict__ V,
                                              const int* __restrict__ cnt,
                                              const int* __restrict__ offs,
                                              const int* __restrict__ bucket,
                                              const float* __restrict__ W,
                                              f16_t* __restrict__ A16,
                                              f16_t* __restrict__ B16,
                                              double* __restrict__ eX64) {
  __shared__ int lst[512];
  __shared__ float red[2];
  int bid = blockIdx.x, t = threadIdx.x;
  int lane = t & 63, wv = t >> 6;
  if (bid < N_EDGES) {
    int m = bid;
    int deg = cnt[m], off = offs[m];
    int n = min(deg, 512);
    for (int j = t; j < n; j += 128) lst[j] = bucket[off + j];
    __syncthreads();
    if (t == 0 && n > 1) {             // ascending-index order == np.add.at order
      for (int a = 1; a < n; ++a) {
        int key = lst[a]; int b = a - 1;
        while (b >= 0 && lst[b] > key) { lst[b + 1] = lst[b]; --b; }
        lst[b + 1] = key;
      }
    }
    __syncthreads();
    float s = 0.f;
    double s64 = 0.0;
    for (int j = 0; j < n; ++j) {
      float xv = X[(size_t)V[lst[j]] * EMB + t];
      s += xv;
      s64 += (double)xv;
    }
    float eXd = s / fmaxf((float)deg, 1.0f);
    eX64[(size_t)m * EMB + t] = s64 / fmax((double)deg, 1.0);
    for (int h = 0; h < NHEAD; ++h) {
      float wd = W[h * EMB + t];
      float val = eXd * wd;
      float ss = val * val;
      for (int o = 32; o > 0; o >>= 1) ss += __shfl_down(ss, o, 64);
      if (lane == 0) red[wv] = ss;
      __syncthreads();
      float nh = 1.0f / fmaxf(sqrtf(red[0] + red[1]), 1e-6f);
      B16[(size_t)m * (NHEAD * EMB) + h * EMB + t] = (f16_t)(eXd * wd * wd * nh);
      __syncthreads();
    }
  } else {
    int nid = bid - N_EDGES;
    float xd = X[(size_t)nid * EMB + t];
    for (int h = 0; h < NHEAD; ++h) {
      float val = xd * W[h * EMB + t];
      float ss = val * val;
      for (int o = 32; o > 0; o >>= 1) ss += __shfl_down(ss, o, 64);
      if (lane == 0) red[wv] = ss;
      __syncthreads();
      float nh = 1.0f / fmaxf(sqrtf(red[0] + red[1]), 1e-6f);
      A16[(size_t)nid * (NHEAD * EMB) + h * EMB + t] = (f16_t)(xd * nh);
      __syncthreads();
    }
  }
}

// ---------------- K5: fp16 MFMA GEMM, BK=64 (halved barrier count) -> S16 ----------------
// R2 PMC on the BK=32 version of this loop: MfmaUtil 11%, VALUBusy 9.5% — ~80% of
// cycles are the per-step vmcnt(0)-drain + 2 barriers, NOT hidden by co-resident
// blocks. With only 16 K-steps that drain count dominates; BK=64 halves it to 8.
// LDS: 32 KB staging unions with the 33 KB C-tile epilogue -> same 4 blocks/CU as
// R6 (no occupancy cliff; m132's regression was 64 KB). Row stride is now 128 B so
// the XOR swizzle widens to 8 slots: LDS slot c of row r holds global chunk
// c ^ (r&7); fragment read applies the same involution (rule #21). 16 lanes per
// fg-group hit 8 distinct slots -> 2-way aliasing = free (m136).
__global__ __launch_bounds__(256) void gemm_k(const f16_t* __restrict__ A16,
                                              const f16_t* __restrict__ B16,
                                              unsigned short* __restrict__ S16) {
  __shared__ __align__(16) unsigned char smem[128 * 132 * 2];  // 33792 B
  f16_t* As = (f16_t*)smem;                    // 16 KB (K-loop)
  f16_t* Bs = (f16_t*)(smem + 16384);          // 16 KB (K-loop)
  unsigned short* Cs = (unsigned short*)smem;  // 33 KB (epilogue, after barrier)
  const int tid  = threadIdx.x;
  const int lane = tid & 63;
  const int wv   = tid >> 6;
  const int m0   = blockIdx.x * 128;       // edge cols
  const int n0   = blockIdx.y * 128;       // node rows
  const int wr   = (wv >> 1) * 64;
  const int wc   = (wv & 1) * 64;
  const int frow = lane & 15;
  const int fg   = lane >> 4;
  const int fsw  = frow & 7;               // 8-slot swizzle key

  f32x4 acc[4][4];
#pragma unroll
  for (int i = 0; i < 4; ++i)
#pragma unroll
    for (int j = 0; j < 4; ++j) acc[i][j] = (f32x4){0.f, 0.f, 0.f, 0.f};

  for (int k0 = 0; k0 < 512; k0 += 64) {
    __syncthreads();
    // stage A,B 128x64-half tiles: 1024 16B-chunks each, 4 per thread per operand
#pragma unroll
    for (int r = 0; r < 4; ++r) {
      int chunk = r * 256 + tid;           // 0..1023
      int row   = chunk >> 3;              // 0..127
      int cb    = ((chunk ^ row) & 7) << 3;  // swizzled half-offset in the 64-half row
      __builtin_amdgcn_global_load_lds(
          (const __attribute__((address_space(1))) void*)
              (A16 + ((size_t)(n0 + row) << 9) + k0 + cb),
          (__attribute__((address_space(3))) void*)(As + (size_t)chunk * 8),
          16, 0, 0);
      __builtin_amdgcn_global_load_lds(
          (const __attribute__((address_space(1))) void*)
              (B16 + ((size_t)(m0 + row) << 9) + k0 + cb),
          (__attribute__((address_space(3))) void*)(Bs + (size_t)chunk * 8),
          16, 0, 0);
    }
    __syncthreads();
#pragma unroll
    for (int ks = 0; ks < 2; ++ks) {
      const int kc = ks * 4 + fg;          // wanted chunk 0..7 within the row
      const int fo = ((kc ^ fsw) & 7) << 3;
      f16x8 a[4], b[4];
#pragma unroll
      for (int i = 0; i < 4; ++i)
        a[i] = *(const f16x8*)(As + (wr + i * 16 + frow) * 64 + fo);
#pragma unroll
      for (int j = 0; j < 4; ++j)
        b[j] = *(const f16x8*)(Bs + (wc + j * 16 + frow) * 64 + fo);
#pragma unroll
      for (int i = 0; i < 4; ++i)
#pragma unroll
        for (int j = 0; j < 4; ++j)
          acc[i][j] = __builtin_amdgcn_mfma_f32_16x16x32_f16(a[i], b[j],
                                                             acc[i][j], 0, 0, 0);
    }
  }
  __syncthreads();   // all waves done with As/Bs before Cs overwrites them
  // C/D layout (m89-verified): col = lane&15, row = (lane>>4)*4 + q
#pragma unroll
  for (int i = 0; i < 4; ++i)
#pragma unroll
    for (int j = 0; j < 4; ++j)
#pragma unroll
      for (int q = 0; q < 4; ++q) {
        int rl = wr + i * 16 + fg * 4 + q;
        int cl = wc + j * 16 + frow;
        f16_t h = (f16_t)(acc[i][j][q] * 0.25f);
        Cs[rl * 132 + cl] = __builtin_bit_cast(unsigned short, h);
      }
  __syncthreads();
  // coalesced copy-out: 128 rows x 32 chunks of 4 cols (8 B, aligned)
  for (int idx = tid; idx < 128 * 32; idx += 256) {
    int r  = idx >> 5;
    int ch = idx & 31;
    *(unsigned long long*)(S16 + (size_t)(n0 + r) * N_EDGES + m0 + ch * 4) =
        *(const unsigned long long*)(Cs + r * 132 + ch * 4);
  }
}

// ---------------- K6: mask existing incidences in S16 (fp16 -inf) ----------------
__global__ void maskset16_k(const int* __restrict__ V, const int* __restrict__ E,
                            unsigned short* __restrict__ S16) {
  int i = blockIdx.x * blockDim.x + threadIdx.x;
  if (i < NNZ) S16[(size_t)V[i] * N_EDGES + E[i]] = 0xFC00u;  // -inf
}

// ---------------- K7: 1/8-SAMPLED 8192-bin histogram over S16 ----------------
__global__ __launch_bounds__(256) void hist16_k(const f16x8* __restrict__ S8,
                                                unsigned* __restrict__ ghist) {
  __shared__ unsigned hh[NBINS];
  for (int i = threadIdx.x; i < NBINS; i += 256) hh[i] = 0;
  __syncthreads();
  const int stride = gridDim.x * blockDim.x;     // multiple of 64
  int j = blockIdx.x * blockDim.x + threadIdx.x;
#define BIN8(v)                                                              \
  _Pragma("unroll") for (int c = 0; c < 8; ++c) {                            \
    float bf = fminf(fmaxf(((float)(v)[c] + 1.0f) * 4096.0f, 0.0f),          \
                     (float)(NBINS - 1));                                    \
    atomicAdd(&hh[(int)bf], 1u);                                             \
  }
#define SIDX(jj) (((jj) >> 6) * 512 + ((jj) & 63))
  for (; j + 3 * stride < SAMP_ITEMS; j += 4 * stride) {
    f16x8 v0 = S8[SIDX(j)];
    f16x8 v1 = S8[SIDX(j + stride)];
    f16x8 v2 = S8[SIDX(j + 2 * stride)];
    f16x8 v3 = S8[SIDX(j + 3 * stride)];
    BIN8(v0) BIN8(v1) BIN8(v2) BIN8(v3)
  }
  for (; j < SAMP_ITEMS; j += stride) { f16x8 v = S8[SIDX(j)]; BIN8(v) }
#undef SIDX
#undef BIN8
  __syncthreads();
  unsigned* gh = ghist + (size_t)(blockIdx.x & (NREP - 1)) * NBINS;
  for (int i2 = threadIdx.x; i2 < NBINS; i2 += 256) {
    unsigned c = hh[i2];
    if (c) atomicAdd(&gh[i2], c);
  }
}

// ---------------- K8: screening threshold from the SAMPLED hist ----------------
__global__ __launch_bounds__(1024) void thresh_k(const unsigned* __restrict__ hist,
                                                 float* __restrict__ T_lo) {
  __shared__ int suff[1024];
  int t = threadIdx.x;
  const int G = NBINS / 1024;
  int b0 = t * G;
  int s = 0;
  for (int j = 0; j < G; ++j) {
    unsigned tb = 0;
    for (int r = 0; r < NREP; ++r) tb += hist[(size_t)r * NBINS + b0 + j];
    s += (int)tb;
  }
  int v = s;
  suff[t] = v; __syncthreads();
  for (int o = 1; o < 1024; o <<= 1) {
    int add = (t + o < 1024) ? suff[t + o] : 0;
    __syncthreads();
    v += add; suff[t] = v;
    __syncthreads();
  }
  int above = (t < 1023) ? suff[t + 1] : 0;
  if (above < K_SAMP && suff[t] >= K_SAMP) {
    int running = above;
    int B = b0;
    for (int b = b0 + G - 1; b >= b0; --b) {
      unsigned tb = 0;
      for (int r = 0; r < NREP; ++r) tb += hist[(size_t)r * NBINS + b];
      running += (int)tb;
      if (running >= K_SAMP) { B = b; break; }
    }
    B = max(B, SLACK_BINS);
    *T_lo = (float)(B - SLACK_BINS) * (1.0f / 4096.0f) - 1.0f;
  }
}

// ---------------- K9: compact candidates, two-level counter (R5-proven) ----------------
__global__ __launch_bounds__(256) void collect16_k(const f16x8* __restrict__ S8,
                                                   const float* __restrict__ T_lo_p,
                                                   unsigned* __restrict__ counter,
                                                   int* __restrict__ ci) {
  __shared__ int lbuf[LBUF];
  __shared__ unsigned lcnt, gbase;
  if (threadIdx.x == 0) lcnt = 0;
  __syncthreads();
  float T = *T_lo_p;
  const int stride = gridDim.x * blockDim.x;
  int i = blockIdx.x * blockDim.x + threadIdx.x;
#define SEL8(v, base)                                                        \
  _Pragma("unroll") for (int c = 0; c < 8; ++c) {                            \
    if ((float)(v)[c] >= T) {                                                \
      unsigned j = atomicAdd(&lcnt, 1u);                                     \
      if (j < LBUF) lbuf[j] = (base) * 8 + c;                                \
      else { unsigned g = atomicAdd(counter, 1u);                            \
             if (g < CAP2) ci[g] = (base) * 8 + c; }                         \
    }                                                                        \
  }
  for (; i + 3 * stride < S_TOTAL / 8; i += 4 * stride) {
    f16x8 v0 = S8[i];
    f16x8 v1 = S8[i + stride];
    f16x8 v2 = S8[i + 2 * stride];
    f16x8 v3 = S8[i + 3 * stride];
    SEL8(v0, i) SEL8(v1, i + stride) SEL8(v2, i + 2 * stride) SEL8(v3, i + 3 * stride)
  }
  for (; i < S_TOTAL / 8; i += stride) { f16x8 v = S8[i]; SEL8(v, i) }
#undef SEL8
  __syncthreads();
  unsigned n = min(lcnt, (unsigned)LBUF);
  if (threadIdx.x == 0) gbase = atomicAdd(counter, n);
  __syncthreads();
  unsigned gb = gbase;
  for (unsigned t = threadIdx.x; t < n; t += 256) {
    unsigned p = gb + t;
    if (p < CAP2) ci[p] = lbuf[t];
  }
}

// ---------------- K10: f64 rescore via precomputed eX64 ----------------
__global__ __launch_bounds__(256) void rescore_k(const float* __restrict__ X,
                                                 const float* __restrict__ W,
                                                 const double* __restrict__ eX64,
                                                 const int* __restrict__ ci,
                                                 const unsigned* __restrict__ counter,
                                                 unsigned long long* __restrict__ ckey) {
  int C = (int)min(*counter, (unsigned)CAP2);
  int wave = threadIdx.x >> 6, lane = threadIdx.x & 63;
  int j = blockIdx.x * 4 + wave;
  if (j >= C) return;
  int pos = ci[j];
  int n = pos >> 13;
  int m = pos & 8191;
  double e0 = eX64[(size_t)m * EMB + lane];
  double e1 = eX64[(size_t)m * EMB + lane + 64];
  const float* xr = X + (size_t)n * EMB;
  double x0 = (double)xr[lane], x1 = (double)xr[lane + 64];
  double s = 0.0;
  for (int h = 0; h < NHEAD; ++h) {
    const float* wr = W + h * EMB;
    double w0 = (double)wr[lane], w1 = (double)wr[lane + 64];
    double xw0 = x0 * w0, xw1 = x1 * w1;
    double ew0 = e0 * w0, ew1 = e1 * w1;
    double an = xw0 * xw0 + xw1 * xw1;
    double ae = ew0 * ew0 + ew1 * ew1;
    double dt = xw0 * ew0 + xw1 * ew1;
    for (int o = 32; o > 0; o >>= 1) {
      an += __shfl_down(an, o, 64);
      ae += __shfl_down(ae, o, 64);
      dt += __shfl_down(dt, o, 64);
    }
    if (lane == 0) {
      double Nn = fmax(sqrt(an), 1e-6);
      double Ne = fmax(sqrt(ae), 1e-6);
      s += dt / (Nn * Ne);
    }
  }
  if (lane == 0) ckey[j] = f64key(s * 0.25);
}

// ---------------- K11: exact k-th largest key via 8-level byte radix select ----------------
// Single-CU scan kernel: x8 MLP per level (L2-latency-bound, same fix as collect R5).
__global__ __launch_bounds__(1024) void kth_k(const unsigned long long* __restrict__ keys,
                                              const unsigned* __restrict__ counter,
                                              unsigned long long* __restrict__ thr) {
  __shared__ unsigned hist[256];
  __shared__ unsigned long long s_prefix;
  __shared__ unsigned s_kleft, s_cgreat;
  int C = (int)min(*counter, (unsigned)CAP2);
  if (threadIdx.x == 0) { s_prefix = 0ULL; s_kleft = K_TOP; s_cgreat = 0u; }
  __syncthreads();
  for (int level = 7; level >= 0; --level) {
    for (int i = threadIdx.x; i < 256; i += 1024) hist[i] = 0;
    __syncthreads();
    unsigned long long prefix = s_prefix;
    unsigned long long pmask = (level == 7) ? 0ULL : (~0ULL << ((level + 1) * 8));
    int sh = level * 8;
    int i = threadIdx.x;
    for (; i + 7 * 1024 < C; i += 8 * 1024) {
      unsigned long long k0 = keys[i];
      unsigned long long k1 = keys[i + 1024];
      unsigned long long k2 = keys[i + 2048];
      unsigned long long k3 = keys[i + 3072];
      unsigned long long k4 = keys[i + 4096];
      unsigned long long k5 = keys[i + 5120];
      unsigned long long k6 = keys[i + 6144];
      unsigned long long k7 = keys[i + 7168];
      if ((k0 & pmask) == prefix) atomicAdd(&hist[(unsigned)((k0 >> sh) & 0xFF)], 1u);
      if ((k1 & pmask) == prefix) atomicAdd(&hist[(unsigned)((k1 >> sh) & 0xFF)], 1u);
      if ((k2 & pmask) == prefix) atomicAdd(&hist[(unsigned)((k2 >> sh) & 0xFF)], 1u);
      if ((k3 & pmask) == prefix) atomicAdd(&hist[(unsigned)((k3 >> sh) & 0xFF)], 1u);
      if ((k4 & pmask) == prefix) atomicAdd(&hist[(unsigned)((k4 >> sh) & 0xFF)], 1u);
      if ((k5 & pmask) == prefix) atomicAdd(&hist[(unsigned)((k5 >> sh) & 0xFF)], 1u);
      if ((k6 & pmask) == prefix) atomicAdd(&hist[(unsigned)((k6 >> sh) & 0xFF)], 1u);
      if ((k7 & pmask) == prefix) atomicAdd(&hist[(unsigned)((k7 >> sh) & 0xFF)], 1u);
    }
    for (; i < C; i += 1024) {
      unsigned long long k = keys[i];
      if ((k & pmask) == prefix) atomicAdd(&hist[(unsigned)((k >> sh) & 0xFF)], 1u);
    }
    __syncthreads();
    if (threadIdx.x == 0) {
      unsigned cum = 0; int b = 0;
      for (int i2 = 255; i2 >= 0; --i2) {
        if (cum + hist[i2] >= s_kleft) { b = i2; break; }
        cum += hist[i2];
      }
      s_prefix |= ((unsigned long long)b << sh);
      s_kleft  -= cum;
      s_cgreat += cum;
    }
    __syncthreads();
  }
  if (threadIdx.x == 0) { thr[0] = s_prefix; thr[1] = (unsigned long long)s_cgreat; }
}

// ---------------- K12: FUSED write (key > thr) + scatterH — disjoint positions ----------------
__global__ void wsH_k(const unsigned long long* __restrict__ keys,
                      const int* __restrict__ ci,
                      const unsigned* __restrict__ counter,
                      const unsigned long long* __restrict__ thr,
                      const float* __restrict__ P, float* __restrict__ out,
                      int* __restrict__ tiebuf, unsigned* __restrict__ tiecnt,
                      const int* __restrict__ V, const int* __restrict__ E) {
  int b = blockIdx.x;
  if (b < WBLK) {
    int C = (int)min(*counter, (unsigned)CAP2);
    int j = b * 256 + threadIdx.x;
    if (j >= C) return;
    unsigned long long k = keys[j];
    unsigned long long t = thr[0];
    if (k > t) {
      unsigned pos = (unsigned)ci[j];
      out[pos] = mask_val(P[pos], pos);
    } else if (k == t) {
      unsigned q = atomicAdd(tiecnt, 1u);
      if (q < TIE_CAP) tiebuf[q] = ci[j];
    }
  } else {
    int i = (b - WBLK) * 256 + threadIdx.x;
    if (i >= NNZ) return;
    unsigned pos = (unsigned)V[i] * (unsigned)N_EDGES + (unsigned)E[i];
    out[pos] = mask_val(P[pos], pos);
  }
}

// ---------------- K13: fill remaining slots from ties, ascending index ----------------
__global__ __launch_bounds__(256) void tiefin_k(const int* __restrict__ tiebuf,
                                                const unsigned* __restrict__ tiecnt,
                                                const unsigned long long* __restrict__ thr,
                                                const float* __restrict__ P,
                                                float* __restrict__ out) {
  __shared__ int idx[TIE_CAP];
  int T = (int)min(*tiecnt, (unsigned)TIE_CAP);
  int need = K_TOP - (int)thr[1];
  if (need <= 0 || T == 0) return;       // uniform exit
  for (int i = threadIdx.x; i < T; i += 256) idx[i] = tiebuf[i];
  __syncthreads();
  if (threadIdx.x == 0 && T > 1) {       // ascending flat index (top_k stable order)
    for (int a = 1; a < T; ++a) {
      int key = idx[a]; int b = a - 1;
      while (b >= 0 && idx[b] > key) { idx[b + 1] = idx[b]; --b; }
      idx[b + 1] = key;
    }
  }
  __syncthreads();
  int m = min(need, T);
  for (int i = threadIdx.x; i < m; i += 256) {
    unsigned pos = (unsigned)idx[i];
    out[pos] = mask_val(P[pos], pos);
  }
}

extern "C" void kernel_launch(void* const* d_in, const int* in_sizes, int n_in,
                              void* d_out, int out_size, void* d_ws, size_t ws_size,
                              hipStream_t stream) {
  const float* X = (const float*)d_in[0];
  // d_in[1] = H (unused: nonzeros are exactly the (V,E) pairs)
  const int*   V = (const int*)d_in[2];
  const int*   E = (const int*)d_in[3];
  const float* P = (const float*)d_in[4];
  const float* W = (const float*)d_in[5];
  float* OUT = (float*)d_out;

  // S16 (fp16 scores, 64 MB) in the upper half of d_out; full d_out memset after use.
  unsigned short* S16 = (unsigned short*)((char*)d_out + (size_t)S_TOTAL * 2);

  // ws layout (~23.4 MB). All zero-init regions contiguous at the front: ONE memset.
  char* w = (char*)d_ws;
  int*      cnt      = (int*)(w + 0);            // 32 KB   [zeroed]
  int*      cursor   = (int*)(w + 32768);        // 32 KB   [zeroed]
  unsigned* counter  = (unsigned*)(w + 65536);   // 4 B     [zeroed]
  float*    T_lo     = (float*)(w + 65540);      // 4 B     [zeroed]
  unsigned* tiecnt   = (unsigned*)(w + 65544);   // 4 B     [zeroed]
  unsigned long long* thr = (unsigned long long*)(w + 65552); // 16 B [zeroed]
  unsigned* ghist    = (unsigned*)(w + 65792);   // 256 KB  [zeroed] -> 327936 (NREP=8)
  int*      offs     = (int*)(w + 590080);       // 32 KB -> 622848
  int*      bucket   = (int*)(w + 622848);       // 256 KB -> 884992
  int*      cand_idx = (int*)(w + 884992);       // 512 KB -> 1409280
  unsigned long long* cand_key = (unsigned long long*)(w + 1409280); // 1 MB -> 2457856
  int*      tiebuf   = (int*)(w + 2457856);      // 4 KB -> 2461952
  f16_t*    A16      = (f16_t*)(w + 2461952);    // 4 MB -> 6656256   (16B aligned)
  f16_t*    B16      = (f16_t*)(w + 6656256);    // 8 MB -> 15044864  (16B aligned)
  double*   eX64     = (double*)(w + 15044864);  // 8 MB -> 23433472  (8B aligned)

  hipMemsetAsync(w, 0, 327936, stream);          // cnt+cursor+scalars+ghist, ONE call

  count_k     <<<NNZ / 256, 256, 0, stream>>>(E, cnt);
  scan_k      <<<1, 1024, 0, stream>>>(cnt, offs);
  scatter_k   <<<NNZ / 256, 256, 0, stream>>>(E, offs, cursor, bucket);
  prep_k      <<<N_EDGES + N_CODES, 128, 0, stream>>>(X, V, cnt, offs, bucket, W,
                                                      A16, B16, eX64);
  gemm_k      <<<dim3(N_EDGES / 128, N_CODES / 128), 256, 0, stream>>>(A16, B16, S16);
  maskset16_k <<<NNZ / 256, 256, 0, stream>>>(V, E, S16);
  hist16_k    <<<256, 256, 0, stream>>>((const f16x8*)S16, ghist);
  thresh_k    <<<1, 1024, 0, stream>>>(ghist, T_lo);
  collect16_k <<<4096, 256, 0, stream>>>((const f16x8*)S16, T_lo, counter, cand_idx);
  rescore_k   <<<CAP2 / 4, 256, 0, stream>>>(X, W, eX64, cand_idx, counter, cand_key);
  kth_k       <<<1, 1024, 0, stream>>>(cand_key, counter, thr);
  hipMemsetAsync(d_out, 0, (size_t)S_TOTAL * 4, stream);  // after S16 consumed
  wsH_k       <<<WBLK + NNZ / 256, 256, 0, stream>>>(cand_key, cand_idx, counter, thr,
                                                     P, OUT, tiebuf, tiecnt, V, E);
  tiefin_k    <<<1, 256, 0, stream>>>(tiebuf, tiecnt, thr, P, OUT);
}

// Round 9
// 496.829 us; speedup vs baseline: 1.0477x; 1.0477x over previous
//
#include <hip/hip_runtime.h>
#include <math.h>

#define N_CODES 4096
#define N_EDGES 8192
#define EMB     128
#define NHEAD   4
#define NNZ     65536
#define K_TOP   6553            // int(0.1 * 65536)
#define K_SAMP  820             // ceil(K_TOP / 8) for the 1/8-sampled histogram
#define S_TOTAL 33554432        // 4096 * 8192
#define NBINS   8192            // 32 KB LDS histogram
#define NREP    16              // global hist replicas (atomic contention /16)
#define CAP2    131072          // candidate cap (pool ~50k at 14-bin slack)
#define SLACK_BINS 14           // 12 (fp16 + GEMM noise) + 2 (1/8-sampling margin)
#define TIE_CAP 1024
#define LBUF    4096            // per-block candidate buffer (16 KB LDS)
#define SAMP_ITEMS (S_TOTAL / 8 / 8)   // 524288 sampled f16x8 items
#define WBLK    (CAP2 / 256)    // 512 write blocks in the fused write/scatter kernel

typedef _Float16 f16_t;
typedef __attribute__((ext_vector_type(8))) _Float16 f16x8;
typedef __attribute__((ext_vector_type(4))) float f32x4;

// ---------------- threefry2x32, JAX partitionable scheme, 32-bit path ----------------
__device__ __forceinline__ unsigned rotl32(unsigned v, int r) {
  return (v << r) | (v >> (32 - r));
}

__device__ float jax_u42(unsigned pos) {
  const unsigned ks0 = 0u, ks1 = 42u, ks2 = 0x1BD11BDAu ^ 0u ^ 42u;
  unsigned x0 = 0u  + ks0;
  unsigned x1 = pos + ks1;
#define TFR(r) { x0 += x1; x1 = rotl32(x1, (r)); x1 ^= x0; }
  TFR(13) TFR(15) TFR(26) TFR(6)   x0 += ks1; x1 += ks2 + 1u;
  TFR(17) TFR(29) TFR(16) TFR(24)  x0 += ks2; x1 += ks0 + 2u;
  TFR(13) TFR(15) TFR(26) TFR(6)   x0 += ks0; x1 += ks1 + 3u;
  TFR(17) TFR(29) TFR(16) TFR(24)  x0 += ks1; x1 += ks2 + 4u;
  TFR(13) TFR(15) TFR(26) TFR(6)   x0 += ks2; x1 += ks0 + 5u;
#undef TFR
  unsigned bits = x0 ^ x1;
  unsigned fb = (bits >> 9) | 0x3f800000u;
  float f = __uint_as_float(fb) - 1.0f;
  const float minv = 1e-6f;
  const float maxv = (float)(1.0 - 1e-6);
  float u = f * (maxv - minv) + minv;
  return fmaxf(minv, u);
}

__device__ float mask_val(float p, unsigned pos) {
  float u = jax_u42(pos);
  float l = (logf(p) - log1pf(-p) + logf(u) - log1pf(-u)) * 2.0f; // /TEMP, TEMP=0.5
  return 1.0f / (1.0f + expf(-l));
}

// f64 -> u64 monotone key (larger double <=> larger key)
__device__ __forceinline__ unsigned long long f64key(double v) {
  long long b = __double_as_longlong(v);
  return (b < 0) ? ~(unsigned long long)b
                 : ((unsigned long long)b | 0x8000000000000000ULL);
}

// ---------------- K1: per-edge counts ----------------
__global__ void count_k(const int* __restrict__ E, int* __restrict__ cnt) {
  int i = blockIdx.x * blockDim.x + threadIdx.x;
  if (i < NNZ) atomicAdd(&cnt[E[i]], 1);
}

// ---------------- K2: exclusive scan of 8192 counts ----------------
__global__ __launch_bounds__(1024) void scan_k(const int* __restrict__ cnt,
                                               int* __restrict__ offs) {
  __shared__ int part[1024];
  int t = threadIdx.x;
  int local[8]; int s = 0;
  for (int j = 0; j < 8; ++j) { local[j] = cnt[t * 8 + j]; s += local[j]; }
  part[t] = s; __syncthreads();
  int v = s;
  for (int o = 1; o < 1024; o <<= 1) {
    int add = (t >= o) ? part[t - o] : 0;
    __syncthreads();
    v += add; part[t] = v;
    __syncthreads();
  }
  int base = v - s;
  for (int j = 0; j < 8; ++j) { offs[t * 8 + j] = base; base += local[j]; }
}

// ---------------- K3: bucket scatter (CSR) ----------------
__global__ void scatter_k(const int* __restrict__ E, const int* __restrict__ offs,
                          int* __restrict__ cursor, int* __restrict__ bucket) {
  int i = blockIdx.x * blockDim.x + threadIdx.x;
  if (i < NNZ) {
    int e = E[i];
    int p = atomicAdd(&cursor[e], 1);
    bucket[offs[e] + p] = i;
  }
}

// ---------------- K4: FUSED prep — edge path (blocks < N_EDGES) + node path ----------------
__global__ __launch_bounds__(128) void prep_k(const float* __restrict__ X,
                                              const int* __restrict__ V,
                                              const int* __restrict__ cnt,
                                              const int* __restrict__ offs,
                                              const int* __restrict__ bucket,
                                              const float* __restrict__ W,
                                              f16_t* __restrict__ A16,
                                              f16_t* __restrict__ B16,
                                              double* __restrict__ eX64) {
  __shared__ int lst[512];
  __shared__ float red[2];
  int bid = blockIdx.x, t = threadIdx.x;
  int lane = t & 63, wv = t >> 6;
  if (bid < N_EDGES) {
    int m = bid;
    int deg = cnt[m], off = offs[m];
    int n = min(deg, 512);
    for (int j = t; j < n; j += 128) lst[j] = bucket[off + j];
    __syncthreads();
    if (t == 0 && n > 1) {             // ascending-index order == np.add.at order
      for (int a = 1; a < n; ++a) {
        int key = lst[a]; int b = a - 1;
        while (b >= 0 && lst[b] > key) { lst[b + 1] = lst[b]; --b; }
        lst[b + 1] = key;
      }
    }
    __syncthreads();
    float s = 0.f;
    double s64 = 0.0;
    for (int j = 0; j < n; ++j) {
      float xv = X[(size_t)V[lst[j]] * EMB + t];
      s += xv;
      s64 += (double)xv;
    }
    float eXd = s / fmaxf((float)deg, 1.0f);
    eX64[(size_t)m * EMB + t] = s64 / fmax((double)deg, 1.0);
    for (int h = 0; h < NHEAD; ++h) {
      float wd = W[h * EMB + t];
      float val = eXd * wd;
      float ss = val * val;
      for (int o = 32; o > 0; o >>= 1) ss += __shfl_down(ss, o, 64);
      if (lane == 0) red[wv] = ss;
      __syncthreads();
      float nh = 1.0f / fmaxf(sqrtf(red[0] + red[1]), 1e-6f);
      B16[(size_t)m * (NHEAD * EMB) + h * EMB + t] = (f16_t)(eXd * wd * wd * nh);
      __syncthreads();
    }
  } else {
    int nid = bid - N_EDGES;
    float xd = X[(size_t)nid * EMB + t];
    for (int h = 0; h < NHEAD; ++h) {
      float val = xd * W[h * EMB + t];
      float ss = val * val;
      for (int o = 32; o > 0; o >>= 1) ss += __shfl_down(ss, o, 64);
      if (lane == 0) red[wv] = ss;
      __syncthreads();
      float nh = 1.0f / fmaxf(sqrtf(red[0] + red[1]), 1e-6f);
      A16[(size_t)nid * (NHEAD * EMB) + h * EMB + t] = (f16_t)(xd * nh);
      __syncthreads();
    }
  }
}

// ---------------- K5: fp16 MFMA GEMM (R1-proven loop, BK=32) -> S16, LDS epilogue ----------------
// R6-measured best: BK=32, 16 steps, 4-slot source-side XOR swizzle (rule #21),
// 0 bank conflicts (R2 PMC). Epilogue stages C in LDS (stride 132) and streams out
// 8B-aligned chunks (R3 PMC: raw 2B stores cost 92 MB WRITE for 67 MB).
__global__ __launch_bounds__(256) void gemm_k(const f16_t* __restrict__ A16,
                                              const f16_t* __restrict__ B16,
                                              unsigned short* __restrict__ S16) {
  __shared__ __align__(16) unsigned char smem[128 * 132 * 2];  // 33792 B
  f16_t* As = (f16_t*)smem;                    // 8 KB   (K-loop)
  f16_t* Bs = (f16_t*)(smem + 8192);           // 8 KB   (K-loop)
  unsigned short* Cs = (unsigned short*)smem;  // 33 KB  (epilogue, after barrier)
  const int tid  = threadIdx.x;
  const int lane = tid & 63;
  const int wv   = tid >> 6;
  const int m0   = blockIdx.x * 128;       // edge cols
  const int n0   = blockIdx.y * 128;       // node rows
  const int wr   = (wv >> 1) * 64;
  const int wc   = (wv & 1) * 64;
  const int frow = lane & 15;
  const int fg   = lane >> 4;
  const int sw   = (frow >> 1) & 3;
  const int fo   = ((fg ^ sw) << 3);

  f32x4 acc[4][4];
#pragma unroll
  for (int i = 0; i < 4; ++i)
#pragma unroll
    for (int j = 0; j < 4; ++j) acc[i][j] = (f32x4){0.f, 0.f, 0.f, 0.f};

  for (int k0 = 0; k0 < 512; k0 += 32) {
    __syncthreads();
#pragma unroll
    for (int r = 0; r < 2; ++r) {
      int chunk = r * 256 + wv * 64 + lane;
      int row   = chunk >> 2;
      int cb    = ((chunk & 3) ^ ((chunk >> 3) & 3)) << 3;
      __builtin_amdgcn_global_load_lds(
          (const __attribute__((address_space(1))) void*)
              (A16 + ((size_t)(n0 + row) << 9) + k0 + cb),
          (__attribute__((address_space(3))) void*)
              (As + (size_t)(r * 256 + wv * 64) * 8),
          16, 0, 0);
      __builtin_amdgcn_global_load_lds(
          (const __attribute__((address_space(1))) void*)
              (B16 + ((size_t)(m0 + row) << 9) + k0 + cb),
          (__attribute__((address_space(3))) void*)
              (Bs + (size_t)(r * 256 + wv * 64) * 8),
          16, 0, 0);
    }
    __syncthreads();
    f16x8 a[4], b[4];
#pragma unroll
    for (int i = 0; i < 4; ++i)
      a[i] = *(const f16x8*)(As + (wr + i * 16 + frow) * 32 + fo);
#pragma unroll
    for (int j = 0; j < 4; ++j)
      b[j] = *(const f16x8*)(Bs + (wc + j * 16 + frow) * 32 + fo);
#pragma unroll
    for (int i = 0; i < 4; ++i)
#pragma unroll
      for (int j = 0; j < 4; ++j)
        acc[i][j] = __builtin_amdgcn_mfma_f32_16x16x32_f16(a[i], b[j], acc[i][j], 0, 0, 0);
  }
  __syncthreads();   // all waves done with As/Bs before Cs overwrites them
  // C/D layout (m89-verified): col = lane&15, row = (lane>>4)*4 + q
#pragma unroll
  for (int i = 0; i < 4; ++i)
#pragma unroll
    for (int j = 0; j < 4; ++j)
#pragma unroll
      for (int q = 0; q < 4; ++q) {
        int rl = wr + i * 16 + fg * 4 + q;
        int cl = wc + j * 16 + frow;
        f16_t h = (f16_t)(acc[i][j][q] * 0.25f);
        Cs[rl * 132 + cl] = __builtin_bit_cast(unsigned short, h);
      }
  __syncthreads();
  // coalesced copy-out: 128 rows x 32 chunks of 4 cols (8 B, aligned)
  for (int idx = tid; idx < 128 * 32; idx += 256) {
    int r  = idx >> 5;
    int ch = idx & 31;
    *(unsigned long long*)(S16 + (size_t)(n0 + r) * N_EDGES + m0 + ch * 4) =
        *(const unsigned long long*)(Cs + r * 132 + ch * 4);
  }
}

// ---------------- K6: mask existing incidences in S16 (fp16 -inf) ----------------
__global__ void maskset16_k(const int* __restrict__ V, const int* __restrict__ E,
                            unsigned short* __restrict__ S16) {
  int i = blockIdx.x * blockDim.x + threadIdx.x;
  if (i < NNZ) S16[(size_t)V[i] * N_EDGES + E[i]] = 0xFC00u;  // -inf
}

// ---------------- K7: 1/8-SAMPLED 8192-bin histogram over S16 ----------------
__global__ __launch_bounds__(256) void hist16_k(const f16x8* __restrict__ S8,
                                                unsigned* __restrict__ ghist) {
  __shared__ unsigned hh[NBINS];
  for (int i = threadIdx.x; i < NBINS; i += 256) hh[i] = 0;
  __syncthreads();
  const int stride = gridDim.x * blockDim.x;     // multiple of 64
  int j = blockIdx.x * blockDim.x + threadIdx.x;
#define BIN8(v)                                                              \
  _Pragma("unroll") for (int c = 0; c < 8; ++c) {                            \
    float bf = fminf(fmaxf(((float)(v)[c] + 1.0f) * 4096.0f, 0.0f),          \
                     (float)(NBINS - 1));                                    \
    atomicAdd(&hh[(int)bf], 1u);                                             \
  }
#define SIDX(jj) (((jj) >> 6) * 512 + ((jj) & 63))
  for (; j + 3 * stride < SAMP_ITEMS; j += 4 * stride) {
    f16x8 v0 = S8[SIDX(j)];
    f16x8 v1 = S8[SIDX(j + stride)];
    f16x8 v2 = S8[SIDX(j + 2 * stride)];
    f16x8 v3 = S8[SIDX(j + 3 * stride)];
    BIN8(v0) BIN8(v1) BIN8(v2) BIN8(v3)
  }
  for (; j < SAMP_ITEMS; j += stride) { f16x8 v = S8[SIDX(j)]; BIN8(v) }
#undef SIDX
#undef BIN8
  __syncthreads();
  unsigned* gh = ghist + (size_t)(blockIdx.x & (NREP - 1)) * NBINS;
  for (int i2 = threadIdx.x; i2 < NBINS; i2 += 256) {
    unsigned c = hh[i2];
    if (c) atomicAdd(&gh[i2], c);
  }
}

// ---------------- K8: screening threshold from the SAMPLED hist ----------------
__global__ __launch_bounds__(1024) void thresh_k(const unsigned* __restrict__ hist,
                                                 float* __restrict__ T_lo) {
  __shared__ int suff[1024];
  int t = threadIdx.x;
  const int G = NBINS / 1024;
  int b0 = t * G;
  int s = 0;
  for (int j = 0; j < G; ++j) {
    unsigned tb = 0;
    for (int r = 0; r < NREP; ++r) tb += hist[(size_t)r * NBINS + b0 + j];
    s += (int)tb;
  }
  int v = s;
  suff[t] = v; __syncthreads();
  for (int o = 1; o < 1024; o <<= 1) {
    int add = (t + o < 1024) ? suff[t + o] : 0;
    __syncthreads();
    v += add; suff[t] = v;
    __syncthreads();
  }
  int above = (t < 1023) ? suff[t + 1] : 0;
  if (above < K_SAMP && suff[t] >= K_SAMP) {
    int running = above;
    int B = b0;
    for (int b = b0 + G - 1; b >= b0; --b) {
      unsigned tb = 0;
      for (int r = 0; r < NREP; ++r) tb += hist[(size_t)r * NBINS + b];
      running += (int)tb;
      if (running >= K_SAMP) { B = b; break; }
    }
    B = max(B, SLACK_BINS);
    *T_lo = (float)(B - SLACK_BINS) * (1.0f / 4096.0f) - 1.0f;
  }
}

// ---------------- K9: compact candidates, two-level counter (R5-proven) ----------------
__global__ __launch_bounds__(256) void collect16_k(const f16x8* __restrict__ S8,
                                                   const float* __restrict__ T_lo_p,
                                                   unsigned* __restrict__ counter,
                                                   int* __restrict__ ci) {
  __shared__ int lbuf[LBUF];
  __shared__ unsigned lcnt, gbase;
  if (threadIdx.x == 0) lcnt = 0;
  __syncthreads();
  float T = *T_lo_p;
  const int stride = gridDim.x * blockDim.x;
  int i = blockIdx.x * blockDim.x + threadIdx.x;
#define SEL8(v, base)                                                        \
  _Pragma("unroll") for (int c = 0; c < 8; ++c) {                            \
    if ((float)(v)[c] >= T) {                                                \
      unsigned j = atomicAdd(&lcnt, 1u);                                     \
      if (j < LBUF) lbuf[j] = (base) * 8 + c;                                \
      else { unsigned g = atomicAdd(counter, 1u);                            \
             if (g < CAP2) ci[g] = (base) * 8 + c; }                         \
    }                                                                        \
  }
  for (; i + 3 * stride < S_TOTAL / 8; i += 4 * stride) {
    f16x8 v0 = S8[i];
    f16x8 v1 = S8[i + stride];
    f16x8 v2 = S8[i + 2 * stride];
    f16x8 v3 = S8[i + 3 * stride];
    SEL8(v0, i) SEL8(v1, i + stride) SEL8(v2, i + 2 * stride) SEL8(v3, i + 3 * stride)
  }
  for (; i < S_TOTAL / 8; i += stride) { f16x8 v = S8[i]; SEL8(v, i) }
#undef SEL8
  __syncthreads();
  unsigned n = min(lcnt, (unsigned)LBUF);
  if (threadIdx.x == 0) gbase = atomicAdd(counter, n);
  __syncthreads();
  unsigned gb = gbase;
  for (unsigned t = threadIdx.x; t < n; t += 256) {
    unsigned p = gb + t;
    if (p < CAP2) ci[p] = lbuf[t];
  }
}

// ---------------- K10: f64 rescore via precomputed eX64 ----------------
__global__ __launch_bounds__(256) void rescore_k(const float* __restrict__ X,
                                                 const float* __restrict__ W,
                                                 const double* __restrict__ eX64,
                                                 const int* __restrict__ ci,
                                                 const unsigned* __restrict__ counter,
                                                 unsigned long long* __restrict__ ckey) {
  int C = (int)min(*counter, (unsigned)CAP2);
  int wave = threadIdx.x >> 6, lane = threadIdx.x & 63;
  int j = blockIdx.x * 4 + wave;
  if (j >= C) return;
  int pos = ci[j];
  int n = pos >> 13;
  int m = pos & 8191;
  double e0 = eX64[(size_t)m * EMB + lane];
  double e1 = eX64[(size_t)m * EMB + lane + 64];
  const float* xr = X + (size_t)n * EMB;
  double x0 = (double)xr[lane], x1 = (double)xr[lane + 64];
  double s = 0.0;
  for (int h = 0; h < NHEAD; ++h) {
    const float* wr = W + h * EMB;
    double w0 = (double)wr[lane], w1 = (double)wr[lane + 64];
    double xw0 = x0 * w0, xw1 = x1 * w1;
    double ew0 = e0 * w0, ew1 = e1 * w1;
    double an = xw0 * xw0 + xw1 * xw1;
    double ae = ew0 * ew0 + ew1 * ew1;
    double dt = xw0 * ew0 + xw1 * ew1;
    for (int o = 32; o > 0; o >>= 1) {
      an += __shfl_down(an, o, 64);
      ae += __shfl_down(ae, o, 64);
      dt += __shfl_down(dt, o, 64);
    }
    if (lane == 0) {
      double Nn = fmax(sqrt(an), 1e-6);
      double Ne = fmax(sqrt(ae), 1e-6);
      s += dt / (Nn * Ne);
    }
  }
  if (lane == 0) ckey[j] = f64key(s * 0.25);
}

// ---------------- K11: exact k-th largest key via 8-level byte radix select ----------------
__global__ __launch_bounds__(1024) void kth_k(const unsigned long long* __restrict__ keys,
                                              const unsigned* __restrict__ counter,
                                              unsigned long long* __restrict__ thr) {
  __shared__ unsigned hist[256];
  __shared__ unsigned long long s_prefix;
  __shared__ unsigned s_kleft, s_cgreat;
  int C = (int)min(*counter, (unsigned)CAP2);
  if (threadIdx.x == 0) { s_prefix = 0ULL; s_kleft = K_TOP; s_cgreat = 0u; }
  __syncthreads();
  for (int level = 7; level >= 0; --level) {
    for (int i = threadIdx.x; i < 256; i += 1024) hist[i] = 0;
    __syncthreads();
    unsigned long long prefix = s_prefix;
    unsigned long long pmask = (level == 7) ? 0ULL : (~0ULL << ((level + 1) * 8));
    int sh = level * 8;
    int i = threadIdx.x;
    for (; i + 3 * 1024 < C; i += 4 * 1024) {        // x4 MLP (collect16 lesson)
      unsigned long long k0 = keys[i];
      unsigned long long k1 = keys[i + 1024];
      unsigned long long k2 = keys[i + 2048];
      unsigned long long k3 = keys[i + 3072];
      if ((k0 & pmask) == prefix) atomicAdd(&hist[(unsigned)((k0 >> sh) & 0xFF)], 1u);
      if ((k1 & pmask) == prefix) atomicAdd(&hist[(unsigned)((k1 >> sh) & 0xFF)], 1u);
      if ((k2 & pmask) == prefix) atomicAdd(&hist[(unsigned)((k2 >> sh) & 0xFF)], 1u);
      if ((k3 & pmask) == prefix) atomicAdd(&hist[(unsigned)((k3 >> sh) & 0xFF)], 1u);
    }
    for (; i < C; i += 1024) {
      unsigned long long k = keys[i];
      if ((k & pmask) == prefix) atomicAdd(&hist[(unsigned)((k >> sh) & 0xFF)], 1u);
    }
    __syncthreads();
    if (threadIdx.x == 0) {
      unsigned cum = 0; int b = 0;
      for (int i2 = 255; i2 >= 0; --i2) {
        if (cum + hist[i2] >= s_kleft) { b = i2; break; }
        cum += hist[i2];
      }
      s_prefix |= ((unsigned long long)b << sh);
      s_kleft  -= cum;
      s_cgreat += cum;
    }
    __syncthreads();
  }
  if (threadIdx.x == 0) { thr[0] = s_prefix; thr[1] = (unsigned long long)s_cgreat; }
}

// ---------------- K12: FUSED write (key > thr) + scatterH — disjoint positions ----------------
__global__ void wsH_k(const unsigned long long* __restrict__ keys,
                      const int* __restrict__ ci,
                      const unsigned* __restrict__ counter,
                      const unsigned long long* __restrict__ thr,
                      const float* __restrict__ P, float* __restrict__ out,
                      int* __restrict__ tiebuf, unsigned* __restrict__ tiecnt,
                      const int* __restrict__ V, const int* __restrict__ E) {
  int b = blockIdx.x;
  if (b < WBLK) {
    int C = (int)min(*counter, (unsigned)CAP2);
    int j = b * 256 + threadIdx.x;
    if (j >= C) return;
    unsigned long long k = keys[j];
    unsigned long long t = thr[0];
    if (k > t) {
      unsigned pos = (unsigned)ci[j];
      out[pos] = mask_val(P[pos], pos);
    } else if (k == t) {
      unsigned q = atomicAdd(tiecnt, 1u);
      if (q < TIE_CAP) tiebuf[q] = ci[j];
    }
  } else {
    int i = (b - WBLK) * 256 + threadIdx.x;
    if (i >= NNZ) return;
    unsigned pos = (unsigned)V[i] * (unsigned)N_EDGES + (unsigned)E[i];
    out[pos] = mask_val(P[pos], pos);
  }
}

// ---------------- K13: fill remaining slots from ties, ascending index ----------------
__global__ __launch_bounds__(256) void tiefin_k(const int* __restrict__ tiebuf,
                                                const unsigned* __restrict__ tiecnt,
                                                const unsigned long long* __restrict__ thr,
                                                const float* __restrict__ P,
                                                float* __restrict__ out) {
  __shared__ int idx[TIE_CAP];
  int T = (int)min(*tiecnt, (unsigned)TIE_CAP);
  int need = K_TOP - (int)thr[1];
  if (need <= 0 || T == 0) return;       // uniform exit
  for (int i = threadIdx.x; i < T; i += 256) idx[i] = tiebuf[i];
  __syncthreads();
  if (threadIdx.x == 0 && T > 1) {       // ascending flat index (top_k stable order)
    for (int a = 1; a < T; ++a) {
      int key = idx[a]; int b = a - 1;
      while (b >= 0 && idx[b] > key) { idx[b + 1] = idx[b]; --b; }
      idx[b + 1] = key;
    }
  }
  __syncthreads();
  int m = min(need, T);
  for (int i = threadIdx.x; i < m; i += 256) {
    unsigned pos = (unsigned)idx[i];
    out[pos] = mask_val(P[pos], pos);
  }
}

extern "C" void kernel_launch(void* const* d_in, const int* in_sizes, int n_in,
                              void* d_out, int out_size, void* d_ws, size_t ws_size,
                              hipStream_t stream) {
  const float* X = (const float*)d_in[0];
  // d_in[1] = H (unused: nonzeros are exactly the (V,E) pairs)
  const int*   V = (const int*)d_in[2];
  const int*   E = (const int*)d_in[3];
  const float* P = (const float*)d_in[4];
  const float* W = (const float*)d_in[5];
  float* OUT = (float*)d_out;

  // S16 (fp16 scores, 64 MB) in the upper half of d_out; full d_out memset after use.
  unsigned short* S16 = (unsigned short*)((char*)d_out + (size_t)S_TOTAL * 2);

  // ws layout (~23.4 MB). All zero-init regions contiguous at the front: ONE memset.
  char* w = (char*)d_ws;
  int*      cnt      = (int*)(w + 0);            // 32 KB   [zeroed]
  int*      cursor   = (int*)(w + 32768);        // 32 KB   [zeroed]
  unsigned* counter  = (unsigned*)(w + 65536);   // 4 B     [zeroed]
  float*    T_lo     = (float*)(w + 65540);      // 4 B     [zeroed]
  unsigned* tiecnt   = (unsigned*)(w + 65544);   // 4 B     [zeroed]
  unsigned long long* thr = (unsigned long long*)(w + 65552); // 16 B [zeroed]
  unsigned* ghist    = (unsigned*)(w + 65792);   // 512 KB  [zeroed] -> 590080
  int*      offs     = (int*)(w + 590080);       // 32 KB -> 622848
  int*      bucket   = (int*)(w + 622848);       // 256 KB -> 884992
  int*      cand_idx = (int*)(w + 884992);       // 512 KB -> 1409280
  unsigned long long* cand_key = (unsigned long long*)(w + 1409280); // 1 MB -> 2457856
  int*      tiebuf   = (int*)(w + 2457856);      // 4 KB -> 2461952
  f16_t*    A16      = (f16_t*)(w + 2461952);    // 4 MB -> 6656256   (16B aligned)
  f16_t*    B16      = (f16_t*)(w + 6656256);    // 8 MB -> 15044864  (16B aligned)
  double*   eX64     = (double*)(w + 15044864);  // 8 MB -> 23433472  (8B aligned)

  hipMemsetAsync(w, 0, 590080, stream);          // cnt+cursor+scalars+ghist, ONE call

  count_k     <<<NNZ / 256, 256, 0, stream>>>(E, cnt);
  scan_k      <<<1, 1024, 0, stream>>>(cnt, offs);
  scatter_k   <<<NNZ / 256, 256, 0, stream>>>(E, offs, cursor, bucket);
  prep_k      <<<N_EDGES + N_CODES, 128, 0, stream>>>(X, V, cnt, offs, bucket, W,
                                                      A16, B16, eX64);
  gemm_k      <<<dim3(N_EDGES / 128, N_CODES / 128), 256, 0, stream>>>(A16, B16, S16);
  maskset16_k <<<NNZ / 256, 256, 0, stream>>>(V, E, S16);
  hist16_k    <<<256, 256, 0, stream>>>((const f16x8*)S16, ghist);
  thresh_k    <<<1, 1024, 0, stream>>>(ghist, T_lo);
  collect16_k <<<2048, 256, 0, stream>>>((const f16x8*)S16, T_lo, counter, cand_idx);
  rescore_k   <<<CAP2 / 4, 256, 0, stream>>>(X, W, eX64, cand_idx, counter, cand_key);
  kth_k       <<<1, 1024, 0, stream>>>(cand_key, counter, thr);
  hipMemsetAsync(d_out, 0, (size_t)S_TOTAL * 4, stream);  // after S16 consumed
  wsH_k       <<<WBLK + NNZ / 256, 256, 0, stream>>>(cand_key, cand_idx, counter, thr,
                                                     P, OUT, tiebuf, tiecnt, V, E);
  tiefin_k    <<<1, 256, 0, stream>>>(tiebuf, tiecnt, thr, P, OUT);
}